// Round 2
// baseline (792.210 us; speedup 1.0000x reference)
//
#include <hip/hip_runtime.h>
#include <hip/hip_bf16.h>

#define BB   64
#define CING 96
#define MIDC 192
#define HH   56
#define WWD  56
#define HWSZ (HH*WWD)
#define COUTC 96
#define RCHUNK 12
#define CGRP 16
#define BNEPS 1e-5f

__device__ __forceinline__ float bf2f(__hip_bfloat16 v){ return __bfloat162float(v); }
__device__ __forceinline__ float siluf(float v){ return v / (1.f + __expf(-v)); }

// zero the SE sums buffer (ws is poisoned 0xAA before every call)
__global__ void k0_zero(float* __restrict__ p, int n){
    int i = blockIdx.x*256 + threadIdx.x;
    if (i < n) p[i] = 0.f;
}

// Fused: expand(1x1)+BN+SiLU -> shift+shuffle -> dw3x3 + id branch -> merge BN -> SiLU
// Emits y (bf16 in ws) and per-(b,oc) sums for SE.
// Block: 256 threads. Grid: (rowchunk=5, chgroup=12, b=64).
__global__ __launch_bounds__(256) void k1_fused(
    const float* __restrict__ x,
    const float* __restrict__ expand_w,
    const float* __restrict__ expand_bn,
    const float* __restrict__ dw_w,
    const float* __restrict__ dw_bn,
    const float* __restrict__ id_w,
    const float* __restrict__ id_bn,
    const float* __restrict__ merge_bn,
    __hip_bfloat16* __restrict__ yout,
    float* __restrict__ sums)
{
    __shared__ float Etile[CGRP][16][WWD];   // 57,344 B
    __shared__ float WeL[CING*CGRP];         //  6,144 B
    __shared__ float w9L[CGRP][9];
    __shared__ float CstL[CGRP];
    __shared__ float escL[CGRP], eshL[CGRP];

    const int t  = threadIdx.x;
    const int rc = blockIdx.x;
    const int cg = blockIdx.y;
    const int b  = blockIdx.z;
    const int r0 = rc * RCHUNK;
    const int Rcur = min(RCHUNK, HH - r0);
    const int TR = Rcur + 4;

    // ---- per-channel setup (folded BN constants) ----
    if (t < CGRP) {
        int oc = cg*CGRP + t;
        int ic = (oc & 3)*48 + (oc >> 2);     // inverse channel-shuffle
        // expand BN (channel index = pre-shuffle channel ic)
        float sc0 = expand_bn[ic] * rsqrtf(expand_bn[3*MIDC+ic] + BNEPS);
        escL[t] = sc0;
        eshL[t] = expand_bn[MIDC+ic] - expand_bn[2*MIDC+ic]*sc0;
        // dw / id / merge BNs (channel index = post-shuffle oc)
        float sc1 = dw_bn[oc]    * rsqrtf(dw_bn[3*MIDC+oc]    + BNEPS);
        float sh1 = dw_bn[MIDC+oc]    - dw_bn[2*MIDC+oc]*sc1;
        float sc2 = id_bn[oc]    * rsqrtf(id_bn[3*MIDC+oc]    + BNEPS);
        float sh2 = id_bn[MIDC+oc]    - id_bn[2*MIDC+oc]*sc2;
        float sc3 = merge_bn[oc] * rsqrtf(merge_bn[3*MIDC+oc] + BNEPS);
        float sh3 = merge_bn[MIDC+oc] - merge_bn[2*MIDC+oc]*sc3;
        float A    = sc3*sc1;                       // onto dw conv output
        float Acen = sc3*sc2*id_w[oc];              // id branch -> center tap
        #pragma unroll
        for (int j = 0; j < 9; j++) w9L[t][j] = A * dw_w[oc*9+j];
        w9L[t][4] += Acen;
        CstL[t] = sc3*(sh1+sh2) + sh3;
    }
    // expand weights for this block's 16 channels, laid [c][k]
    for (int i = t; i < CING*CGRP; i += 256) {
        int k = i & (CGRP-1);
        int c = i >> 4;
        int oc = cg*CGRP + k;
        int ic = (oc & 3)*48 + (oc >> 2);
        WeL[c*CGRP + k] = expand_w[ic*CING + c];
    }
    __syncthreads();

    // ---- phase 1: expand + BN + SiLU into LDS tile (rows r0-2 .. r0+Rcur+1) ----
    const int TOT = TR * WWD;
    for (int p = t; p < TOT; p += 256) {
        int tr = p / WWD, col = p - tr*WWD;
        int gr = r0 - 2 + tr;
        if (gr >= 0 && gr < HH) {
            float acc[CGRP];
            #pragma unroll
            for (int k = 0; k < CGRP; k++) acc[k] = 0.f;
            const float* xp = x + ((size_t)b*CING*HH + gr)*WWD + col;
            for (int c = 0; c < CING; c++) {
                float xv = xp[(size_t)c*HWSZ];
                #pragma unroll
                for (int k = 0; k < CGRP; k++) acc[k] += xv * WeL[c*CGRP+k];
            }
            #pragma unroll
            for (int k = 0; k < CGRP; k++)
                Etile[k][tr][col] = siluf(acc[k]*escL[k] + eshL[k]);
        } else {
            #pragma unroll
            for (int k = 0; k < CGRP; k++) Etile[k][tr][col] = 0.f;
        }
    }
    __syncthreads();

    // ---- phase 2: shifted dw 3x3 + folded BNs + SiLU; write y, reduce sums ----
    const int k   = t >> 4;
    const int l16 = t & 15;
    const int oc  = cg*CGRP + k;
    const int g   = k & 3;                 // (cg*16+k)&3 == k&3
    const int dy  = (g==0) ? -1 : (g==2 ? 1 : 0);
    const int dx  = (g==1) ? -1 : (g==3 ? 1 : 0);
    float partial = 0.f;
    const int NP = Rcur * WWD;
    for (int p = l16; p < NP; p += 16) {
        int rr = p / WWD, col = p - rr*WWD;
        int gr = r0 + rr;
        float s9 = 0.f;
        #pragma unroll
        for (int di = 0; di < 3; di++) {
            int ys = gr + di - 1;          // conv tap row (pre-shift)
            int yy = ys + dy;              // shifted source row in E
            bool yok = (ys >= 0) & (ys < HH) & (yy >= 0) & (yy < HH);
            int tyr = yy - r0 + 2;
            #pragma unroll
            for (int dj = 0; dj < 3; dj++) {
                int xs = col + dj - 1;
                int xx = xs + dx;
                if (yok && xs >= 0 && xs < WWD && xx >= 0 && xx < WWD)
                    s9 += w9L[k][di*3+dj] * Etile[k][tyr][xx];
            }
        }
        float yv = siluf(s9 + CstL[k]);
        yout[((size_t)b*MIDC + oc)*HWSZ + gr*WWD + col] = __float2bfloat16(yv);
        partial += yv;
    }
    partial += __shfl_xor(partial, 1);
    partial += __shfl_xor(partial, 2);
    partial += __shfl_xor(partial, 4);
    partial += __shfl_xor(partial, 8);
    if (l16 == 0) atomicAdd(&sums[b*MIDC + oc], partial);
}

// SE: mean -> grouped reduce (12 groups, 16->2) -> ReLU -> grouped expand (2->16) -> sigmoid
__global__ __launch_bounds__(192) void k2_se(
    const float* __restrict__ sums,
    const float* __restrict__ se_red_w,
    const float* __restrict__ se_red_b,
    const float* __restrict__ se_exp_w,
    const float* __restrict__ se_exp_b,
    float* __restrict__ sews)
{
    __shared__ float meanL[MIDC];
    __shared__ float redL[24];
    const int b = blockIdx.x, t = threadIdx.x;
    meanL[t] = sums[b*MIDC + t] * (1.f/(float)HWSZ);
    __syncthreads();
    if (t < 24) {
        int g = t >> 1;
        float a = se_red_b[t];
        #pragma unroll
        for (int i = 0; i < 16; i++) a += meanL[g*16+i] * se_red_w[t*16+i];
        redL[t] = fmaxf(a, 0.f);
    }
    __syncthreads();
    int g = t >> 4;
    float a = se_exp_b[t] + redL[g*2]   * se_exp_w[t*2]
                          + redL[g*2+1] * se_exp_w[t*2+1];
    sews[b*MIDC + t] = 1.f/(1.f + __expf(-a));
}

// proj 1x1 (192->96) with SE folded into weights + BN + residual + SiLU
// Grid: (pixel tile 13, b 64, o-half 2). Block 256 (1 pixel/thread, 48 outputs).
__global__ __launch_bounds__(256) void k3_proj(
    const __hip_bfloat16* __restrict__ yws,
    const float* __restrict__ sews,
    const float* __restrict__ proj_w,
    const float* __restrict__ proj_bn,
    const float* __restrict__ x,
    float* __restrict__ out)
{
    __shared__ float WpL[MIDC*48];   // [c][j], se pre-folded  (36,864 B)
    __shared__ float seL[MIDC];
    __shared__ float psc[48], psh[48];
    const int t = threadIdx.x;
    const int tile = blockIdx.x, b = blockIdx.y, h = blockIdx.z;
    if (t < MIDC) seL[t] = sews[b*MIDC + t];
    if (t < 48) {
        int o = h*48 + t;
        float sc = proj_bn[o] * rsqrtf(proj_bn[3*COUTC+o] + BNEPS);
        psc[t] = sc;
        psh[t] = proj_bn[COUTC+o] - proj_bn[2*COUTC+o]*sc;
    }
    __syncthreads();
    for (int i = t; i < MIDC*48; i += 256) {
        int c = i / 48, j = i - c*48;
        int o = h*48 + j;
        WpL[c*48 + j] = proj_w[o*MIDC + c] * seL[c];
    }
    __syncthreads();
    const int s = tile*256 + t;
    if (s >= HWSZ) return;
    float acc[48];
    #pragma unroll
    for (int j = 0; j < 48; j++) acc[j] = 0.f;
    const __hip_bfloat16* yp = yws + (size_t)b*MIDC*HWSZ + s;
    for (int c = 0; c < MIDC; c++) {
        float yv = bf2f(yp[(size_t)c*HWSZ]);
        #pragma unroll
        for (int j = 0; j < 48; j++) acc[j] += yv * WpL[c*48+j];
    }
    #pragma unroll
    for (int j = 0; j < 48; j++) {
        int o = h*48 + j;
        size_t idx = ((size_t)b*COUTC + o)*HWSZ + s;
        float v = acc[j]*psc[j] + psh[j] + x[idx];
        out[idx] = __float2bfloat16(siluf(v)) ;  // placeholder, fixed below
    }
}

// NOTE: out is fp32 — the line above must store fp32. Correct store kernel:
__global__ __launch_bounds__(256) void k3_proj_f32(
    const __hip_bfloat16* __restrict__ yws,
    const float* __restrict__ sews,
    const float* __restrict__ proj_w,
    const float* __restrict__ proj_bn,
    const float* __restrict__ x,
    float* __restrict__ out)
{
    __shared__ float WpL[MIDC*48];
    __shared__ float seL[MIDC];
    __shared__ float psc[48], psh[48];
    const int t = threadIdx.x;
    const int tile = blockIdx.x, b = blockIdx.y, h = blockIdx.z;
    if (t < MIDC) seL[t] = sews[b*MIDC + t];
    if (t < 48) {
        int o = h*48 + t;
        float sc = proj_bn[o] * rsqrtf(proj_bn[3*COUTC+o] + BNEPS);
        psc[t] = sc;
        psh[t] = proj_bn[COUTC+o] - proj_bn[2*COUTC+o]*sc;
    }
    __syncthreads();
    for (int i = t; i < MIDC*48; i += 256) {
        int c = i / 48, j = i - c*48;
        int o = h*48 + j;
        WpL[c*48 + j] = proj_w[o*MIDC + c] * seL[c];
    }
    __syncthreads();
    const int s = tile*256 + t;
    if (s >= HWSZ) return;
    float acc[48];
    #pragma unroll
    for (int j = 0; j < 48; j++) acc[j] = 0.f;
    const __hip_bfloat16* yp = yws + (size_t)b*MIDC*HWSZ + s;
    for (int c = 0; c < MIDC; c++) {
        float yv = bf2f(yp[(size_t)c*HWSZ]);
        #pragma unroll
        for (int j = 0; j < 48; j++) acc[j] += yv * WpL[c*48+j];
    }
    #pragma unroll
    for (int j = 0; j < 48; j++) {
        int o = h*48 + j;
        size_t idx = ((size_t)b*COUTC + o)*HWSZ + s;
        float v = acc[j]*psc[j] + psh[j] + x[idx];
        out[idx] = siluf(v);
    }
}

extern "C" void kernel_launch(void* const* d_in, const int* in_sizes, int n_in,
                              void* d_out, int out_size, void* d_ws, size_t ws_size,
                              hipStream_t stream)
{
    const float* x         = (const float*)d_in[0];
    const float* expand_w  = (const float*)d_in[1];
    const float* expand_bn = (const float*)d_in[2];
    const float* dw_w      = (const float*)d_in[3];
    const float* dw_bn     = (const float*)d_in[4];
    const float* id_w      = (const float*)d_in[5];
    const float* id_bn     = (const float*)d_in[6];
    const float* merge_bn  = (const float*)d_in[7];
    const float* se_red_w  = (const float*)d_in[8];
    const float* se_red_b  = (const float*)d_in[9];
    const float* se_exp_w  = (const float*)d_in[10];
    const float* se_exp_b  = (const float*)d_in[11];
    const float* proj_w    = (const float*)d_in[12];
    const float* proj_bn   = (const float*)d_in[13];

    char* base = (char*)d_ws;
    __hip_bfloat16* yws = (__hip_bfloat16*)base;                 // 64*192*3136 bf16 = 77,070,336 B
    const size_t ybytes = (size_t)BB*MIDC*HWSZ*sizeof(__hip_bfloat16);
    float* sums = (float*)(base + ybytes);                       // 12,288 f32
    float* sews = sums + BB*MIDC;                                // 12,288 f32

    k0_zero<<<dim3((BB*MIDC + 255)/256), dim3(256), 0, stream>>>(sums, BB*MIDC);
    k1_fused<<<dim3(5, 12, BB), dim3(256), 0, stream>>>(
        x, expand_w, expand_bn, dw_w, dw_bn, id_w, id_bn, merge_bn, yws, sums);
    k2_se<<<dim3(BB), dim3(192), 0, stream>>>(
        sums, se_red_w, se_red_b, se_exp_w, se_exp_b, sews);
    k3_proj_f32<<<dim3((HWSZ + 255)/256, BB, 2), dim3(256), 0, stream>>>(
        yws, sews, proj_w, proj_bn, x, (float*)d_out);
}

// Round 3
// 384.031 us; speedup vs baseline: 2.0629x; 2.0629x over previous
//
#include <hip/hip_runtime.h>
#include <hip/hip_bf16.h>

#define BB   64
#define CING 96
#define MIDC 192
#define HH   56
#define WWD  56
#define HWSZ (HH*WWD)
#define COUTC 96
#define BNEPS 1e-5f

typedef __attribute__((ext_vector_type(8))) short short8;
typedef __attribute__((ext_vector_type(4))) float float4v;
typedef unsigned short ushort_t;
typedef unsigned int uint_t;

__device__ __forceinline__ float siluf(float v){ return v / (1.f + __expf(-v)); }
__device__ __forceinline__ ushort_t f2bs(float f){
    uint_t u = __float_as_uint(f);
    uint_t r = u + 0x7FFFu + ((u >> 16) & 1u);   // RNE; inputs are finite
    return (ushort_t)(r >> 16);
}
__device__ __forceinline__ float bs2f(ushort_t u){
    return __uint_as_float(((uint_t)u) << 16);
}

// ---------------- k0: fold BNs, reorder+cast weights (runs every call) ----------
__global__ __launch_bounds__(256) void k0_setup(
    const float* __restrict__ expand_w, const float* __restrict__ expand_bn,
    const float* __restrict__ dw_w, const float* __restrict__ dw_bn,
    const float* __restrict__ id_w, const float* __restrict__ id_bn,
    const float* __restrict__ merge_bn,
    const float* __restrict__ proj_w, const float* __restrict__ proj_bn,
    ushort_t* __restrict__ Aexp, float* __restrict__ ebias,
    float* __restrict__ w9f, float* __restrict__ cstf,
    ushort_t* __restrict__ Aproj, float* __restrict__ pscf, float* __restrict__ pshf)
{
    int i = blockIdx.x*256 + threadIdx.x;
    if (i < 4608) {                       // expand A: [m=192][k=96], BN-scale folded, shuffled
        int m = i/24, kq = (i%24)*4;
        int ic = (m&3)*48 + (m>>2);
        float sc0 = expand_bn[ic]*rsqrtf(expand_bn[3*MIDC+ic]+BNEPS);
        #pragma unroll
        for (int j=0;j<4;j++) Aexp[m*96+kq+j] = f2bs(expand_w[ic*96+kq+j]*sc0);
        if (kq==0) ebias[m] = expand_bn[MIDC+ic] - expand_bn[2*MIDC+ic]*sc0;
    } else if (i < 9216) {                // proj A: [m=96][k=192]
        int ii = i-4608; int m = ii/48, kq = (ii%48)*4;
        #pragma unroll
        for (int j=0;j<4;j++) Aproj[m*MIDC+kq+j] = f2bs(proj_w[m*MIDC+kq+j]);
        if (kq==0){
            float sc = proj_bn[m]*rsqrtf(proj_bn[3*COUTC+m]+BNEPS);
            pscf[m]=sc; pshf[m]=proj_bn[COUTC+m]-proj_bn[2*COUTC+m]*sc;
        }
    } else if (i < 9408) {                // dw folded taps
        int oc = i-9216;
        float sc1 = dw_bn[oc]    * rsqrtf(dw_bn[3*MIDC+oc]    + BNEPS);
        float sh1 = dw_bn[MIDC+oc]    - dw_bn[2*MIDC+oc]*sc1;
        float sc2 = id_bn[oc]    * rsqrtf(id_bn[3*MIDC+oc]    + BNEPS);
        float sh2 = id_bn[MIDC+oc]    - id_bn[2*MIDC+oc]*sc2;
        float sc3 = merge_bn[oc] * rsqrtf(merge_bn[3*MIDC+oc] + BNEPS);
        float sh3 = merge_bn[MIDC+oc] - merge_bn[2*MIDC+oc]*sc3;
        float A = sc3*sc1;
        #pragma unroll
        for (int j=0;j<9;j++) w9f[oc*9+j] = A*dw_w[oc*9+j];
        w9f[oc*9+4] += sc3*sc2*id_w[oc];
        cstf[oc] = sc3*(sh1+sh2) + sh3;
    }
}

// ---------------- k1: expand GEMM (MFMA) + BN + SiLU -> E (bf16, shuffled order) --
#define LDA1 104
#define LDB1 66
__global__ __launch_bounds__(256) void k1_expand(
    const float* __restrict__ x,
    const ushort_t* __restrict__ Aexp,
    const float* __restrict__ ebias,
    ushort_t* __restrict__ EY)
{
    __shared__ __align__(16) ushort_t As[MIDC*LDA1];
    __shared__ __align__(16) ushort_t Bs[CING*LDB1];
    __shared__ float ebL[MIDC];
    const int t = threadIdx.x;
    const int p0 = blockIdx.x*64, b = blockIdx.y;

    for (int i = t; i < 4608; i += 256) {           // stage A: 192x96
        int m = i/24, kq = (i%24)*4;
        *(ushort4*)(&As[m*LDA1 + kq]) = *(const ushort4*)(Aexp + m*96 + kq);
    }
    if (t < MIDC) ebL[t] = ebias[t];
    for (int i = t; i < 1536; i += 256) {           // stage B: 96 x 64 px, fp32->bf16
        int c = i >> 4, pq = (i & 15)*4;
        float4 v = *(const float4*)(x + (size_t)(b*CING + c)*HWSZ + p0 + pq);
        ushort4 u; u.x=f2bs(v.x); u.y=f2bs(v.y); u.z=f2bs(v.z); u.w=f2bs(v.w);
        *(ushort4*)(&Bs[c*LDB1 + pq]) = u;
    }
    __syncthreads();

    const int lane = t & 63, wv = t >> 6;
    const int n0 = wv*16, l = lane & 15, q = lane >> 4;
    float4v acc[12];
    #pragma unroll
    for (int i=0;i<12;i++) acc[i] = (float4v){0.f,0.f,0.f,0.f};
    #pragma unroll
    for (int ks = 0; ks < 3; ks++) {
        const int k0 = ks*32;
        short8 bf;
        #pragma unroll
        for (int j = 0; j < 8; j++)
            bf[j] = (short)Bs[(k0 + q*8 + j)*LDB1 + n0 + l];
        #pragma unroll
        for (int mt = 0; mt < 12; mt++) {
            short8 af = *(const short8*)(&As[(mt*16 + l)*LDA1 + k0 + q*8]);
            acc[mt] = __builtin_amdgcn_mfma_f32_16x16x32_bf16(af, bf, acc[mt], 0,0,0);
        }
    }
    const size_t base = (size_t)(b*MIDC)*HWSZ + p0 + n0 + l;
    #pragma unroll
    for (int mt = 0; mt < 12; mt++) {
        #pragma unroll
        for (int r = 0; r < 4; r++) {
            int m = mt*16 + q*4 + r;
            EY[base + (size_t)m*HWSZ] = f2bs(siluf(acc[mt][r] + ebL[m]));
        }
    }
}

// ---------------- k2: shifted dw3x3 + SiLU, in-place E->y, SE sums --------------
__global__ __launch_bounds__(256) void k2_dw(
    ushort_t* __restrict__ EY,
    const float* __restrict__ w9f,
    const float* __restrict__ cstf,
    float* __restrict__ sums)
{
    __shared__ __align__(16) ushort_t Ep[HWSZ];
    __shared__ float wred[4];
    const int t = threadIdx.x;
    const int oc = blockIdx.x, b = blockIdx.y;
    ushort_t* plane = EY + (size_t)(b*MIDC + oc)*HWSZ;
    for (int i = t; i < HWSZ/8; i += 256)           // 392 x 16B
        *(uint4*)(&Ep[i*8]) = *(const uint4*)(plane + i*8);
    const int g = oc & 3;
    const int dy = (g==0)?-1:(g==2?1:0);
    const int dx = (g==1)?-1:(g==3?1:0);
    float w[9];
    #pragma unroll
    for (int j=0;j<9;j++) w[j] = w9f[oc*9+j];
    const float cst = cstf[oc];
    __syncthreads();

    float partial = 0.f;
    for (int p = t; p < HWSZ; p += 256) {
        int r = p / WWD, col = p - r*WWD;
        float s9 = 0.f;
        #pragma unroll
        for (int di = 0; di < 3; di++) {
            int ys = r + di - 1, yy = ys + dy;
            bool yok = ((unsigned)ys < HH) & ((unsigned)yy < HH);
            #pragma unroll
            for (int dj = 0; dj < 3; dj++) {
                int xs = col + dj - 1, xx = xs + dx;
                if (yok && (unsigned)xs < WWD && (unsigned)xx < WWD)
                    s9 += w[di*3+dj] * bs2f(Ep[yy*WWD + xx]);
            }
        }
        float yv = siluf(s9 + cst);
        plane[p] = f2bs(yv);
        partial += yv;
    }
    #pragma unroll
    for (int off=1; off<64; off<<=1) partial += __shfl_xor(partial, off);
    if ((t&63)==0) wred[t>>6] = partial;
    __syncthreads();
    if (t==0) sums[b*MIDC+oc] = wred[0]+wred[1]+wred[2]+wred[3];
}

// ---------------- k3: SE -------------------------------------------------------
__global__ __launch_bounds__(192) void k3_se(
    const float* __restrict__ sums,
    const float* __restrict__ se_red_w, const float* __restrict__ se_red_b,
    const float* __restrict__ se_exp_w, const float* __restrict__ se_exp_b,
    float* __restrict__ sews)
{
    __shared__ float meanL[MIDC];
    __shared__ float redL[24];
    const int b = blockIdx.x, t = threadIdx.x;
    meanL[t] = sums[b*MIDC + t] * (1.f/(float)HWSZ);
    __syncthreads();
    if (t < 24) {
        int g = t >> 1;
        float a = se_red_b[t];
        #pragma unroll
        for (int i = 0; i < 16; i++) a += meanL[g*16+i] * se_red_w[t*16+i];
        redL[t] = fmaxf(a, 0.f);
    }
    __syncthreads();
    int g = t >> 4;
    float a = se_exp_b[t] + redL[g*2]*se_exp_w[t*2] + redL[g*2+1]*se_exp_w[t*2+1];
    sews[b*MIDC + t] = 1.f/(1.f + __expf(-a));
}

// ---------------- k4: proj GEMM (MFMA, SE folded) + BN + residual + SiLU --------
#define LDA4 200
#define LDB4 66
__global__ __launch_bounds__(256) void k4_proj(
    const ushort_t* __restrict__ EY,
    const float* __restrict__ sews,
    const ushort_t* __restrict__ Aproj,
    const float* __restrict__ pscf, const float* __restrict__ pshf,
    const float* __restrict__ x,
    float* __restrict__ out)
{
    __shared__ __align__(16) ushort_t Ap[COUTC*LDA4];
    __shared__ __align__(16) ushort_t Bs[MIDC*LDB4];
    __shared__ float seL[MIDC];
    __shared__ float pscL[COUTC], pshL[COUTC];
    const int t = threadIdx.x;
    const int p0 = blockIdx.x*64, b = blockIdx.y;
    if (t < MIDC) seL[t] = sews[b*MIDC + t];
    if (t < COUTC) { pscL[t] = pscf[t]; pshL[t] = pshf[t]; }
    for (int i = t; i < 4608; i += 256) {           // stage A: 96x192
        int m = i/48, kq = (i%48)*4;
        *(ushort4*)(&Ap[m*LDA4 + kq]) = *(const ushort4*)(Aproj + m*MIDC + kq);
    }
    __syncthreads();
    for (int i = t; i < 3072; i += 256) {           // stage B: y * se, 192 x 64 px
        int c = i >> 4, pq = (i & 15)*4;
        ushort4 u = *(const ushort4*)(EY + (size_t)(b*MIDC + c)*HWSZ + p0 + pq);
        float sc = seL[c];
        ushort4 o;
        o.x = f2bs(bs2f(u.x)*sc); o.y = f2bs(bs2f(u.y)*sc);
        o.z = f2bs(bs2f(u.z)*sc); o.w = f2bs(bs2f(u.w)*sc);
        *(ushort4*)(&Bs[c*LDB4 + pq]) = o;
    }
    __syncthreads();

    const int lane = t & 63, wv = t >> 6;
    const int n0 = wv*16, l = lane & 15, q = lane >> 4;
    float4v acc[6];
    #pragma unroll
    for (int i=0;i<6;i++) acc[i] = (float4v){0.f,0.f,0.f,0.f};
    #pragma unroll
    for (int ks = 0; ks < 6; ks++) {
        const int k0 = ks*32;
        short8 bf;
        #pragma unroll
        for (int j = 0; j < 8; j++)
            bf[j] = (short)Bs[(k0 + q*8 + j)*LDB4 + n0 + l];
        #pragma unroll
        for (int mt = 0; mt < 6; mt++) {
            short8 af = *(const short8*)(&Ap[(mt*16 + l)*LDA4 + k0 + q*8]);
            acc[mt] = __builtin_amdgcn_mfma_f32_16x16x32_bf16(af, bf, acc[mt], 0,0,0);
        }
    }
    const size_t pix = (size_t)p0 + n0 + l;
    #pragma unroll
    for (int mt = 0; mt < 6; mt++) {
        #pragma unroll
        for (int r = 0; r < 4; r++) {
            int m = mt*16 + q*4 + r;
            size_t idx = (size_t)(b*COUTC + m)*HWSZ + pix;
            float v = acc[mt][r]*pscL[m] + pshL[m] + x[idx];
            out[idx] = siluf(v);
        }
    }
}

extern "C" void kernel_launch(void* const* d_in, const int* in_sizes, int n_in,
                              void* d_out, int out_size, void* d_ws, size_t ws_size,
                              hipStream_t stream)
{
    const float* x         = (const float*)d_in[0];
    const float* expand_w  = (const float*)d_in[1];
    const float* expand_bn = (const float*)d_in[2];
    const float* dw_w      = (const float*)d_in[3];
    const float* dw_bn     = (const float*)d_in[4];
    const float* id_w      = (const float*)d_in[5];
    const float* id_bn     = (const float*)d_in[6];
    const float* merge_bn  = (const float*)d_in[7];
    const float* se_red_w  = (const float*)d_in[8];
    const float* se_red_b  = (const float*)d_in[9];
    const float* se_exp_w  = (const float*)d_in[10];
    const float* se_exp_b  = (const float*)d_in[11];
    const float* proj_w    = (const float*)d_in[12];
    const float* proj_bn   = (const float*)d_in[13];

    char* base = (char*)d_ws;
    size_t off = 0;
    ushort_t* EY   = (ushort_t*)(base + off); off += (size_t)BB*MIDC*HWSZ*2;  // 77,070,336
    float* sums    = (float*)(base + off);    off += BB*MIDC*4;
    float* sews    = (float*)(base + off);    off += BB*MIDC*4;
    ushort_t* Aexp = (ushort_t*)(base + off); off += MIDC*CING*2;
    ushort_t* Aproj= (ushort_t*)(base + off); off += COUTC*MIDC*2;
    float* ebias   = (float*)(base + off);    off += MIDC*4;
    float* w9f     = (float*)(base + off);    off += MIDC*9*4;
    float* cstf    = (float*)(base + off);    off += MIDC*4;
    float* pscf    = (float*)(base + off);    off += COUTC*4;
    float* pshf    = (float*)(base + off);    off += COUTC*4;

    k0_setup<<<dim3(37), dim3(256), 0, stream>>>(
        expand_w, expand_bn, dw_w, dw_bn, id_w, id_bn, merge_bn, proj_w, proj_bn,
        Aexp, ebias, w9f, cstf, Aproj, pscf, pshf);
    k1_expand<<<dim3(HWSZ/64, BB), dim3(256), 0, stream>>>(x, Aexp, ebias, EY);
    k2_dw<<<dim3(MIDC, BB), dim3(256), 0, stream>>>(EY, w9f, cstf, sums);
    k3_se<<<dim3(BB), dim3(192), 0, stream>>>(
        sums, se_red_w, se_red_b, se_exp_w, se_exp_b, sews);
    k4_proj<<<dim3(HWSZ/64, BB), dim3(256), 0, stream>>>(
        EY, sews, Aproj, pscf, pshf, x, (float*)d_out);
}

// Round 4
// 334.359 us; speedup vs baseline: 2.3693x; 1.1486x over previous
//
#include <hip/hip_runtime.h>
#include <hip/hip_bf16.h>

#define BB   64
#define CING 96
#define MIDC 192
#define HH   56
#define WWD  56
#define HWSZ (HH*WWD)
#define COUTC 96
#define BNEPS 1e-5f

typedef __attribute__((ext_vector_type(8))) short short8;
typedef __attribute__((ext_vector_type(8))) unsigned short ushort8v;
typedef __attribute__((ext_vector_type(4))) float float4v;
typedef unsigned short ushort_t;
typedef unsigned int uint_t;

__device__ __forceinline__ float siluf(float v){ return v / (1.f + __expf(-v)); }
__device__ __forceinline__ ushort_t f2bs(float f){
    uint_t u = __float_as_uint(f);
    uint_t r = u + 0x7FFFu + ((u >> 16) & 1u);   // RNE; inputs are finite
    return (ushort_t)(r >> 16);
}
__device__ __forceinline__ float bs2f(ushort_t u){
    return __uint_as_float(((uint_t)u) << 16);
}

// ---------------- k0: fold BNs, reorder+cast weights ---------------------------
__global__ __launch_bounds__(256) void k0_setup(
    const float* __restrict__ expand_w, const float* __restrict__ expand_bn,
    const float* __restrict__ dw_w, const float* __restrict__ dw_bn,
    const float* __restrict__ id_w, const float* __restrict__ id_bn,
    const float* __restrict__ merge_bn,
    const float* __restrict__ proj_w, const float* __restrict__ proj_bn,
    ushort_t* __restrict__ Aexp, float* __restrict__ ebias,
    float* __restrict__ w9f, float* __restrict__ cstf,
    ushort_t* __restrict__ Aproj, float* __restrict__ pscf, float* __restrict__ pshf)
{
    int i = blockIdx.x*256 + threadIdx.x;
    if (i < 4608) {                       // expand A: [m=192][k=96], BN-scale folded, shuffled
        int m = i/24, kq = (i%24)*4;
        int ic = (m&3)*48 + (m>>2);
        float sc0 = expand_bn[ic]*rsqrtf(expand_bn[3*MIDC+ic]+BNEPS);
        #pragma unroll
        for (int j=0;j<4;j++) Aexp[m*96+kq+j] = f2bs(expand_w[ic*96+kq+j]*sc0);
        if (kq==0) ebias[m] = expand_bn[MIDC+ic] - expand_bn[2*MIDC+ic]*sc0;
    } else if (i < 9216) {                // proj A: [m=96][k=192]
        int ii = i-4608; int m = ii/48, kq = (ii%48)*4;
        #pragma unroll
        for (int j=0;j<4;j++) Aproj[m*MIDC+kq+j] = f2bs(proj_w[m*MIDC+kq+j]);
        if (kq==0){
            float sc = proj_bn[m]*rsqrtf(proj_bn[3*COUTC+m]+BNEPS);
            pscf[m]=sc; pshf[m]=proj_bn[COUTC+m]-proj_bn[2*COUTC+m]*sc;
        }
    } else if (i < 9408) {                // dw folded taps
        int oc = i-9216;
        float sc1 = dw_bn[oc]    * rsqrtf(dw_bn[3*MIDC+oc]    + BNEPS);
        float sh1 = dw_bn[MIDC+oc]    - dw_bn[2*MIDC+oc]*sc1;
        float sc2 = id_bn[oc]    * rsqrtf(id_bn[3*MIDC+oc]    + BNEPS);
        float sh2 = id_bn[MIDC+oc]    - id_bn[2*MIDC+oc]*sc2;
        float sc3 = merge_bn[oc] * rsqrtf(merge_bn[3*MIDC+oc] + BNEPS);
        float sh3 = merge_bn[MIDC+oc] - merge_bn[2*MIDC+oc]*sc3;
        float A = sc3*sc1;
        #pragma unroll
        for (int j=0;j<9;j++) w9f[oc*9+j] = A*dw_w[oc*9+j];
        w9f[oc*9+4] += sc3*sc2*id_w[oc];
        cstf[oc] = sc3*(sh1+sh2) + sh3;
    }
}

// ---------------- k1: expand GEMM (MFMA) + BN + SiLU -> E ----------------------
#define LDA1 104
#define LDB1T 104
__global__ __launch_bounds__(256) void k1_expand(
    const float* __restrict__ x,
    const ushort_t* __restrict__ Aexp,
    const float* __restrict__ ebias,
    ushort_t* __restrict__ EY)
{
    __shared__ __align__(16) ushort_t As[MIDC*LDA1];    // 39,936 B
    __shared__ __align__(16) ushort_t BsT[64*LDB1T];    // 13,312 B  [n][k]
    __shared__ float ebL[MIDC];
    const int t = threadIdx.x;
    const int p0 = blockIdx.x*64, b = blockIdx.y;

    for (int i = t; i < 4608; i += 256) {               // stage A: 192x96
        int m = i/24, kq = (i%24)*4;
        *(ushort4*)(&As[m*LDA1 + kq]) = *(const ushort4*)(Aexp + m*96 + kq);
    }
    if (t < MIDC) ebL[t] = ebias[t];
    {                                                   // stage B transposed: [n=64][k=96]
        const int n  = t & 63;
        const int kb = (t >> 6)*24;
        #pragma unroll
        for (int ii = 0; ii < 3; ii++) {
            int k8 = kb + ii*8;
            const float* xp = x + ((size_t)(b*CING + k8))*HWSZ + p0 + n;
            ushort8v u;
            #pragma unroll
            for (int j = 0; j < 8; j++) u[j] = f2bs(xp[(size_t)j*HWSZ]);
            *(ushort8v*)(&BsT[n*LDB1T + k8]) = u;
        }
    }
    __syncthreads();

    const int lane = t & 63, wv = t >> 6;
    const int l = lane & 15, q = lane >> 4;
    float4v acc[3][4];
    #pragma unroll
    for (int mi=0;mi<3;mi++)
        #pragma unroll
        for (int nt=0;nt<4;nt++) acc[mi][nt] = (float4v){0.f,0.f,0.f,0.f};
    #pragma unroll
    for (int ks = 0; ks < 3; ks++) {
        const int k0 = ks*32;
        short8 bf[4];
        #pragma unroll
        for (int nt = 0; nt < 4; nt++)
            bf[nt] = *(const short8*)(&BsT[(nt*16 + l)*LDB1T + k0 + q*8]);
        #pragma unroll
        for (int mi = 0; mi < 3; mi++) {
            short8 af = *(const short8*)(&As[((wv*3+mi)*16 + l)*LDA1 + k0 + q*8]);
            #pragma unroll
            for (int nt = 0; nt < 4; nt++)
                acc[mi][nt] = __builtin_amdgcn_mfma_f32_16x16x32_bf16(af, bf[nt], acc[mi][nt], 0,0,0);
        }
    }
    #pragma unroll
    for (int mi = 0; mi < 3; mi++) {
        #pragma unroll
        for (int r = 0; r < 4; r++) {
            int m = (wv*3+mi)*16 + q*4 + r;
            float eb = ebL[m];
            size_t rowb = (size_t)(b*MIDC + m)*HWSZ + p0 + l;
            #pragma unroll
            for (int nt = 0; nt < 4; nt++)
                EY[rowb + nt*16] = f2bs(siluf(acc[mi][nt][r] + eb));
        }
    }
}

// ---------------- k2: shifted dw3x3 + SiLU, in-place E->y, SE sums --------------
#define PR 64
__global__ __launch_bounds__(256) void k2_dw(
    ushort_t* __restrict__ EY,
    const float* __restrict__ w9f,
    const float* __restrict__ cstf,
    float* __restrict__ sums)
{
    __shared__ __align__(16) ushort_t P[58*PR];   // shifted+masked plane, 1-zero border
    __shared__ float wred[4];
    const int t = threadIdx.x;
    const int oc = blockIdx.x, b = blockIdx.y;
    ushort_t* plane = EY + (size_t)(b*MIDC + oc)*HWSZ;
    const int g = oc & 3;
    const int dy = (g==0)?-1:(g==2?1:0);
    const int dx = (g==1)?-1:(g==3?1:0);
    float w9[9];
    #pragma unroll
    for (int j=0;j<9;j++) w9[j] = w9f[oc*9+j];
    const float cst = cstf[oc];

    // stage P[rp][cp]: tap (ys,xs)=(rp-1,cp-1); value = masked E[ys+dy][xs+dx]
    for (int i = t; i < 58*PR; i += 256) {
        int rp = i >> 6, cp = i & 63;
        int ys = rp - 1, xs = cp - 1;
        int yy = ys + dy, xx = xs + dx;
        ushort_t val = 0;
        if (cp < 58 && (unsigned)ys < HH && (unsigned)xs < WWD &&
            (unsigned)yy < HH && (unsigned)xx < WWD)
            val = plane[yy*WWD + xx];
        P[i] = val;
    }
    __syncthreads();

    float partial = 0.f;
    for (int ci = t; ci < 392; ci += 256) {       // 56 rows x 7 col-chunks of 8
        int r = ci / 7, cc = (ci - r*7)*8;
        float o[8];
        #pragma unroll
        for (int j=0;j<8;j++) o[j] = 0.f;
        #pragma unroll
        for (int dr = 0; dr < 3; dr++) {
            const ushort_t* row = &P[(r+dr)*PR + cc];
            ushort8v a8 = *(const ushort8v*)row;
            ushort4  a4 = *(const ushort4*)(row + 8);
            float f[12];
            #pragma unroll
            for (int j=0;j<8;j++) f[j] = bs2f(a8[j]);
            f[8]=bs2f(a4.x); f[9]=bs2f(a4.y); f[10]=bs2f(a4.z); f[11]=bs2f(a4.w);
            float w0 = w9[dr*3], w1 = w9[dr*3+1], w2 = w9[dr*3+2];
            #pragma unroll
            for (int j=0;j<8;j++) o[j] += w0*f[j] + w1*f[j+1] + w2*f[j+2];
        }
        ushort8v yv8;
        #pragma unroll
        for (int j=0;j<8;j++) {
            float yv = siluf(o[j] + cst);
            yv8[j] = f2bs(yv);
            partial += yv;
        }
        *(ushort8v*)(&plane[r*WWD + cc]) = yv8;
    }
    #pragma unroll
    for (int off=1; off<64; off<<=1) partial += __shfl_xor(partial, off);
    if ((t&63)==0) wred[t>>6] = partial;
    __syncthreads();
    if (t==0) sums[b*MIDC+oc] = wred[0]+wred[1]+wred[2]+wred[3];
}

// ---------------- k3: SE -------------------------------------------------------
__global__ __launch_bounds__(192) void k3_se(
    const float* __restrict__ sums,
    const float* __restrict__ se_red_w, const float* __restrict__ se_red_b,
    const float* __restrict__ se_exp_w, const float* __restrict__ se_exp_b,
    float* __restrict__ sews)
{
    __shared__ float meanL[MIDC];
    __shared__ float redL[24];
    const int b = blockIdx.x, t = threadIdx.x;
    meanL[t] = sums[b*MIDC + t] * (1.f/(float)HWSZ);
    __syncthreads();
    if (t < 24) {
        int g = t >> 1;
        float a = se_red_b[t];
        #pragma unroll
        for (int i = 0; i < 16; i++) a += meanL[g*16+i] * se_red_w[t*16+i];
        redL[t] = fmaxf(a, 0.f);
    }
    __syncthreads();
    int g = t >> 4;
    float a = se_exp_b[t] + redL[g*2]*se_exp_w[t*2] + redL[g*2+1]*se_exp_w[t*2+1];
    sews[b*MIDC + t] = 1.f/(1.f + __expf(-a));
}

// ---------------- k4: proj GEMM (MFMA, SE folded) + BN + residual + SiLU --------
#define LDA4 200
#define LDB4T 200
__global__ __launch_bounds__(256) void k4_proj(
    const ushort_t* __restrict__ EY,
    const float* __restrict__ sews,
    const ushort_t* __restrict__ Aproj,
    const float* __restrict__ pscf, const float* __restrict__ pshf,
    const float* __restrict__ x,
    float* __restrict__ out)
{
    __shared__ __align__(16) ushort_t Ap[COUTC*LDA4];    // 38,400 B
    __shared__ __align__(16) ushort_t BsT[64*LDB4T];     // 25,600 B  [n][k]
    __shared__ float pscL[COUTC], pshL[COUTC];
    const int t = threadIdx.x;
    const int p0 = blockIdx.x*64, b = blockIdx.y;
    if (t < COUTC) { pscL[t] = pscf[t]; pshL[t] = pshf[t]; }
    for (int i = t; i < 4608; i += 256) {               // stage A: 96x192
        int m = i/48, kq = (i%48)*4;
        *(ushort4*)(&Ap[m*LDA4 + kq]) = *(const ushort4*)(Aproj + m*MIDC + kq);
    }
    {                                                   // stage B transposed: [n=64][k=192], SE folded
        const int n  = t & 63;
        const int kb = (t >> 6)*48;
        const float* sew = sews + b*MIDC;
        #pragma unroll
        for (int ii = 0; ii < 6; ii++) {
            int k8 = kb + ii*8;
            const ushort_t* ep = EY + ((size_t)(b*MIDC + k8))*HWSZ + p0 + n;
            ushort8v u;
            #pragma unroll
            for (int j = 0; j < 8; j++)
                u[j] = f2bs(bs2f(ep[(size_t)j*HWSZ]) * sew[k8+j]);
            *(ushort8v*)(&BsT[n*LDB4T + k8]) = u;
        }
    }
    __syncthreads();

    const int lane = t & 63, wv = t >> 6;
    const int l = lane & 15, q = lane >> 4;
    const int mh = wv >> 1, nh = wv & 1;
    float4v acc[3][2];
    #pragma unroll
    for (int mi=0;mi<3;mi++)
        #pragma unroll
        for (int nt=0;nt<2;nt++) acc[mi][nt] = (float4v){0.f,0.f,0.f,0.f};
    #pragma unroll
    for (int ks = 0; ks < 6; ks++) {
        const int k0 = ks*32;
        short8 bf[2];
        #pragma unroll
        for (int nt = 0; nt < 2; nt++)
            bf[nt] = *(const short8*)(&BsT[(nh*32 + nt*16 + l)*LDB4T + k0 + q*8]);
        #pragma unroll
        for (int mi = 0; mi < 3; mi++) {
            short8 af = *(const short8*)(&Ap[((mh*3+mi)*16 + l)*LDA4 + k0 + q*8]);
            #pragma unroll
            for (int nt = 0; nt < 2; nt++)
                acc[mi][nt] = __builtin_amdgcn_mfma_f32_16x16x32_bf16(af, bf[nt], acc[mi][nt], 0,0,0);
        }
    }
    #pragma unroll
    for (int mi = 0; mi < 3; mi++) {
        #pragma unroll
        for (int r = 0; r < 4; r++) {
            int m = (mh*3+mi)*16 + q*4 + r;
            float sc = pscL[m], sh = pshL[m];
            size_t rowb = (size_t)(b*COUTC + m)*HWSZ + p0 + nh*32 + l;
            #pragma unroll
            for (int nt = 0; nt < 2; nt++) {
                size_t idx = rowb + nt*16;
                out[idx] = siluf(acc[mi][nt][r]*sc + sh + x[idx]);
            }
        }
    }
}

extern "C" void kernel_launch(void* const* d_in, const int* in_sizes, int n_in,
                              void* d_out, int out_size, void* d_ws, size_t ws_size,
                              hipStream_t stream)
{
    const float* x         = (const float*)d_in[0];
    const float* expand_w  = (const float*)d_in[1];
    const float* expand_bn = (const float*)d_in[2];
    const float* dw_w      = (const float*)d_in[3];
    const float* dw_bn     = (const float*)d_in[4];
    const float* id_w      = (const float*)d_in[5];
    const float* id_bn     = (const float*)d_in[6];
    const float* merge_bn  = (const float*)d_in[7];
    const float* se_red_w  = (const float*)d_in[8];
    const float* se_red_b  = (const float*)d_in[9];
    const float* se_exp_w  = (const float*)d_in[10];
    const float* se_exp_b  = (const float*)d_in[11];
    const float* proj_w    = (const float*)d_in[12];
    const float* proj_bn   = (const float*)d_in[13];

    char* base = (char*)d_ws;
    size_t off = 0;
    ushort_t* EY   = (ushort_t*)(base + off); off += (size_t)BB*MIDC*HWSZ*2;  // 77,070,336
    float* sums    = (float*)(base + off);    off += BB*MIDC*4;
    float* sews    = (float*)(base + off);    off += BB*MIDC*4;
    ushort_t* Aexp = (ushort_t*)(base + off); off += MIDC*CING*2;
    ushort_t* Aproj= (ushort_t*)(base + off); off += COUTC*MIDC*2;
    float* ebias   = (float*)(base + off);    off += MIDC*4;
    float* w9f     = (float*)(base + off);    off += MIDC*9*4;
    float* cstf    = (float*)(base + off);    off += MIDC*4;
    float* pscf    = (float*)(base + off);    off += COUTC*4;
    float* pshf    = (float*)(base + off);    off += COUTC*4;

    k0_setup<<<dim3(37), dim3(256), 0, stream>>>(
        expand_w, expand_bn, dw_w, dw_bn, id_w, id_bn, merge_bn, proj_w, proj_bn,
        Aexp, ebias, w9f, cstf, Aproj, pscf, pshf);
    k1_expand<<<dim3(HWSZ/64, BB), dim3(256), 0, stream>>>(x, Aexp, ebias, EY);
    k2_dw<<<dim3(MIDC, BB), dim3(256), 0, stream>>>(EY, w9f, cstf, sums);
    k3_se<<<dim3(BB), dim3(192), 0, stream>>>(
        sums, se_red_w, se_red_b, se_exp_w, se_exp_b, sews);
    k4_proj<<<dim3(HWSZ/64, BB), dim3(256), 0, stream>>>(
        EY, sews, Aproj, pscf, pshf, x, (float*)d_out);
}

// Round 5
// 289.179 us; speedup vs baseline: 2.7395x; 1.1562x over previous
//
#include <hip/hip_runtime.h>
#include <hip/hip_bf16.h>

#define BB   64
#define CING 96
#define MIDC 192
#define HH   56
#define WWD  56
#define HWSZ (HH*WWD)
#define COUTC 96
#define BNEPS 1e-5f

typedef __attribute__((ext_vector_type(8))) short short8;
typedef __attribute__((ext_vector_type(8))) unsigned short ushort8v;
typedef __attribute__((ext_vector_type(4))) float float4v;
typedef unsigned short ushort_t;
typedef unsigned int uint_t;

__device__ __forceinline__ float siluf(float v){ return v / (1.f + __expf(-v)); }
__device__ __forceinline__ ushort_t f2bs(float f){
    uint_t u = __float_as_uint(f);
    uint_t r = u + 0x7FFFu + ((u >> 16) & 1u);   // RNE; inputs are finite
    return (ushort_t)(r >> 16);
}
__device__ __forceinline__ float bs2f(ushort_t u){
    return __uint_as_float(((uint_t)u) << 16);
}

// ---------------- k0: fold BNs, reorder+cast weights ---------------------------
__global__ __launch_bounds__(256) void k0_setup(
    const float* __restrict__ expand_w, const float* __restrict__ expand_bn,
    const float* __restrict__ dw_w, const float* __restrict__ dw_bn,
    const float* __restrict__ id_w, const float* __restrict__ id_bn,
    const float* __restrict__ merge_bn,
    const float* __restrict__ proj_w, const float* __restrict__ proj_bn,
    ushort_t* __restrict__ Aexp, float* __restrict__ ebias,
    float* __restrict__ w9f, float* __restrict__ cstf,
    ushort_t* __restrict__ Aproj, float* __restrict__ pscf, float* __restrict__ pshf)
{
    int i = blockIdx.x*256 + threadIdx.x;
    if (i < 4608) {                       // expand A: [m=192][k=96], BN-scale folded, shuffled
        int m = i/24, kq = (i%24)*4;
        int ic = (m&3)*48 + (m>>2);
        float sc0 = expand_bn[ic]*rsqrtf(expand_bn[3*MIDC+ic]+BNEPS);
        #pragma unroll
        for (int j=0;j<4;j++) Aexp[m*96+kq+j] = f2bs(expand_w[ic*96+kq+j]*sc0);
        if (kq==0) ebias[m] = expand_bn[MIDC+ic] - expand_bn[2*MIDC+ic]*sc0;
    } else if (i < 9216) {                // proj A: [m=96][k=192]
        int ii = i-4608; int m = ii/48, kq = (ii%48)*4;
        #pragma unroll
        for (int j=0;j<4;j++) Aproj[m*MIDC+kq+j] = f2bs(proj_w[m*MIDC+kq+j]);
        if (kq==0){
            float sc = proj_bn[m]*rsqrtf(proj_bn[3*COUTC+m]+BNEPS);
            pscf[m]=sc; pshf[m]=proj_bn[COUTC+m]-proj_bn[2*COUTC+m]*sc;
        }
    } else if (i < 9408) {                // dw folded taps
        int oc = i-9216;
        float sc1 = dw_bn[oc]    * rsqrtf(dw_bn[3*MIDC+oc]    + BNEPS);
        float sh1 = dw_bn[MIDC+oc]    - dw_bn[2*MIDC+oc]*sc1;
        float sc2 = id_bn[oc]    * rsqrtf(id_bn[3*MIDC+oc]    + BNEPS);
        float sh2 = id_bn[MIDC+oc]    - id_bn[2*MIDC+oc]*sc2;
        float sc3 = merge_bn[oc] * rsqrtf(merge_bn[3*MIDC+oc] + BNEPS);
        float sh3 = merge_bn[MIDC+oc] - merge_bn[2*MIDC+oc]*sc3;
        float A = sc3*sc1;
        #pragma unroll
        for (int j=0;j<9;j++) w9f[oc*9+j] = A*dw_w[oc*9+j];
        w9f[oc*9+4] += sc3*sc2*id_w[oc];
        cstf[oc] = sc3*(sh1+sh2) + sh3;
    }
}

// ---------------- k1: expand GEMM (MFMA, A in regs) + BN + SiLU -> E -----------
#define LDB1T 104
__global__ __launch_bounds__(256) void k1_expand(
    const float* __restrict__ x,
    const ushort_t* __restrict__ Aexp,
    const float* __restrict__ ebias,
    ushort_t* __restrict__ EY)
{
    __shared__ __align__(16) ushort_t BsT[64*LDB1T];    // 13,312 B  [n][k]
    __shared__ float ebL[MIDC];
    const int t = threadIdx.x;
    const int p0 = blockIdx.x*64, b = blockIdx.y;

    if (t < MIDC) ebL[t] = ebias[t];
    {                                                   // stage B transposed: [n=64][k=96]
        const int n  = t & 63;
        const int kb = (t >> 6)*24;
        #pragma unroll
        for (int ii = 0; ii < 3; ii++) {
            int k8 = kb + ii*8;
            const float* xp = x + ((size_t)(b*CING + k8))*HWSZ + p0 + n;
            ushort8v u;
            #pragma unroll
            for (int j = 0; j < 8; j++) u[j] = f2bs(xp[(size_t)j*HWSZ]);
            *(ushort8v*)(&BsT[n*LDB1T + k8]) = u;
        }
    }

    const int lane = t & 63, wv = t >> 6;
    const int l = lane & 15, q = lane >> 4;
    // A fragments straight from global (L2-resident 37 KB)
    short8 af[3][3];
    #pragma unroll
    for (int ks = 0; ks < 3; ks++)
        #pragma unroll
        for (int mi = 0; mi < 3; mi++)
            af[ks][mi] = *(const short8*)(Aexp + ((wv*3+mi)*16 + l)*96 + ks*32 + q*8);
    __syncthreads();

    float4v acc[3][4];
    #pragma unroll
    for (int mi=0;mi<3;mi++)
        #pragma unroll
        for (int nt=0;nt<4;nt++) acc[mi][nt] = (float4v){0.f,0.f,0.f,0.f};
    #pragma unroll
    for (int ks = 0; ks < 3; ks++) {
        const int k0 = ks*32;
        short8 bf[4];
        #pragma unroll
        for (int nt = 0; nt < 4; nt++)
            bf[nt] = *(const short8*)(&BsT[(nt*16 + l)*LDB1T + k0 + q*8]);
        #pragma unroll
        for (int mi = 0; mi < 3; mi++)
            #pragma unroll
            for (int nt = 0; nt < 4; nt++)
                acc[mi][nt] = __builtin_amdgcn_mfma_f32_16x16x32_bf16(af[ks][mi], bf[nt], acc[mi][nt], 0,0,0);
    }
    #pragma unroll
    for (int mi = 0; mi < 3; mi++) {
        #pragma unroll
        for (int r = 0; r < 4; r++) {
            int m = (wv*3+mi)*16 + q*4 + r;
            float eb = ebL[m];
            size_t rowb = (size_t)(b*MIDC + m)*HWSZ + p0 + l;
            #pragma unroll
            for (int nt = 0; nt < 4; nt++)
                EY[rowb + nt*16] = f2bs(siluf(acc[mi][nt][r] + eb));
        }
    }
}

// ---------------- k2: shifted dw3x3 + SiLU, register-rolling, in-place ---------
// One wave per (b,oc) plane; lane = column. No LDS.
__global__ __launch_bounds__(256) void k2_dw(
    ushort_t* __restrict__ EY,
    const float* __restrict__ w9f,
    const float* __restrict__ cstf,
    float* __restrict__ sums)
{
    const int t = threadIdx.x;
    const int lane = t & 63, wv = t >> 6;
    const int oc = blockIdx.x*4 + wv;
    const int b  = blockIdx.y;
    ushort_t* plane = EY + (size_t)(b*MIDC + oc)*HWSZ;
    const int g  = oc & 3;
    const int dy = (g==0)?-1:(g==2?1:0);
    const int dx = (g==1)?-1:(g==3?1:0);
    float w9[9];
    #pragma unroll
    for (int j=0;j<9;j++) w9[j] = w9f[oc*9+j];
    const float cst = cstf[oc];

    const int c  = lane;
    const int cx = c + dx;
    const bool laneok = (c < WWD) & (cx >= 0) & (cx < WWD);
    const int cxc = min(max(cx, 0), WWD-1);
    const bool cval = (c < WWD);

    float p1 = 0.f, p0 = 0.f, partial = 0.f;
    for (int y = -1; y <= HH; y++) {
        int yy = y + dy;
        float val = 0.f;
        if (y >= 0 && y < HH && yy >= 0 && yy < HH) {   // wave-uniform
            float v = bs2f(plane[yy*WWD + cxc]);
            val = laneok ? v : 0.f;
        }
        float vl = __shfl_up(val, 1);  if (lane == 0) vl = 0.f;
        float vr = __shfl_down(val, 1);                // lane63 garbage: c>=56, never stored
        float a0 = w9[0]*vl + w9[1]*val + w9[2]*vr;    // -> out[y+1]
        float a1 = w9[3]*vl + w9[4]*val + w9[5]*vr;    // -> out[y]
        float a2 = w9[6]*vl + w9[7]*val + w9[8]*vr;    // -> out[y-1]
        if (y >= 1) {
            float yv = siluf(p1 + a2 + cst);
            if (cval) {
                plane[(y-1)*WWD + c] = f2bs(yv);
                partial += yv;
            }
        }
        p1 = p0 + a1;
        p0 = a0;
    }
    #pragma unroll
    for (int off=1; off<64; off<<=1) partial += __shfl_xor(partial, off);
    if (lane == 0) sums[b*MIDC + oc] = partial;
}

// ---------------- k3: SE -------------------------------------------------------
__global__ __launch_bounds__(192) void k3_se(
    const float* __restrict__ sums,
    const float* __restrict__ se_red_w, const float* __restrict__ se_red_b,
    const float* __restrict__ se_exp_w, const float* __restrict__ se_exp_b,
    float* __restrict__ sews)
{
    __shared__ float meanL[MIDC];
    __shared__ float redL[24];
    const int b = blockIdx.x, t = threadIdx.x;
    meanL[t] = sums[b*MIDC + t] * (1.f/(float)HWSZ);
    __syncthreads();
    if (t < 24) {
        int g = t >> 1;
        float a = se_red_b[t];
        #pragma unroll
        for (int i = 0; i < 16; i++) a += meanL[g*16+i] * se_red_w[t*16+i];
        redL[t] = fmaxf(a, 0.f);
    }
    __syncthreads();
    int g = t >> 4;
    float a = se_exp_b[t] + redL[g*2]*se_exp_w[t*2] + redL[g*2+1]*se_exp_w[t*2+1];
    sews[b*MIDC + t] = 1.f/(1.f + __expf(-a));
}

// ---------------- k4: proj GEMM (MFMA, A in regs, SE folded) + BN + res + SiLU --
#define LDB4T 200
__global__ __launch_bounds__(256) void k4_proj(
    const ushort_t* __restrict__ EY,
    const float* __restrict__ sews,
    const ushort_t* __restrict__ Aproj,
    const float* __restrict__ pscf, const float* __restrict__ pshf,
    const float* __restrict__ x,
    float* __restrict__ out)
{
    __shared__ __align__(16) ushort_t BsT[64*LDB4T];     // 25,600 B  [n][k]
    __shared__ float pscL[COUTC], pshL[COUTC];
    const int t = threadIdx.x;
    const int p0 = blockIdx.x*64, b = blockIdx.y;
    if (t < COUTC) { pscL[t] = pscf[t]; pshL[t] = pshf[t]; }
    {                                                   // stage B transposed, SE folded
        const int n  = t & 63;
        const int kb = (t >> 6)*48;
        const float* sew = sews + b*MIDC;
        #pragma unroll
        for (int ii = 0; ii < 6; ii++) {
            int k8 = kb + ii*8;
            const ushort_t* ep = EY + ((size_t)(b*MIDC + k8))*HWSZ + p0 + n;
            ushort8v u;
            #pragma unroll
            for (int j = 0; j < 8; j++)
                u[j] = f2bs(bs2f(ep[(size_t)j*HWSZ]) * sew[k8+j]);
            *(ushort8v*)(&BsT[n*LDB4T + k8]) = u;
        }
    }

    const int lane = t & 63, wv = t >> 6;
    const int l = lane & 15, q = lane >> 4;
    const int mh = wv >> 1, nh = wv & 1;
    short8 af[6][3];
    #pragma unroll
    for (int ks = 0; ks < 6; ks++)
        #pragma unroll
        for (int mi = 0; mi < 3; mi++)
            af[ks][mi] = *(const short8*)(Aproj + ((mh*3+mi)*16 + l)*MIDC + ks*32 + q*8);
    __syncthreads();

    float4v acc[3][2];
    #pragma unroll
    for (int mi=0;mi<3;mi++)
        #pragma unroll
        for (int nt=0;nt<2;nt++) acc[mi][nt] = (float4v){0.f,0.f,0.f,0.f};
    #pragma unroll
    for (int ks = 0; ks < 6; ks++) {
        const int k0 = ks*32;
        short8 bf[2];
        #pragma unroll
        for (int nt = 0; nt < 2; nt++)
            bf[nt] = *(const short8*)(&BsT[(nh*32 + nt*16 + l)*LDB4T + k0 + q*8]);
        #pragma unroll
        for (int mi = 0; mi < 3; mi++)
            #pragma unroll
            for (int nt = 0; nt < 2; nt++)
                acc[mi][nt] = __builtin_amdgcn_mfma_f32_16x16x32_bf16(af[ks][mi], bf[nt], acc[mi][nt], 0,0,0);
    }
    #pragma unroll
    for (int mi = 0; mi < 3; mi++) {
        #pragma unroll
        for (int r = 0; r < 4; r++) {
            int m = (mh*3+mi)*16 + q*4 + r;
            float sc = pscL[m], sh = pshL[m];
            size_t rowb = (size_t)(b*COUTC + m)*HWSZ + p0 + nh*32 + l;
            #pragma unroll
            for (int nt = 0; nt < 2; nt++) {
                size_t idx = rowb + nt*16;
                out[idx] = siluf(acc[mi][nt][r]*sc + sh + x[idx]);
            }
        }
    }
}

extern "C" void kernel_launch(void* const* d_in, const int* in_sizes, int n_in,
                              void* d_out, int out_size, void* d_ws, size_t ws_size,
                              hipStream_t stream)
{
    const float* x         = (const float*)d_in[0];
    const float* expand_w  = (const float*)d_in[1];
    const float* expand_bn = (const float*)d_in[2];
    const float* dw_w      = (const float*)d_in[3];
    const float* dw_bn     = (const float*)d_in[4];
    const float* id_w      = (const float*)d_in[5];
    const float* id_bn     = (const float*)d_in[6];
    const float* merge_bn  = (const float*)d_in[7];
    const float* se_red_w  = (const float*)d_in[8];
    const float* se_red_b  = (const float*)d_in[9];
    const float* se_exp_w  = (const float*)d_in[10];
    const float* se_exp_b  = (const float*)d_in[11];
    const float* proj_w    = (const float*)d_in[12];
    const float* proj_bn   = (const float*)d_in[13];

    char* base = (char*)d_ws;
    size_t off = 0;
    ushort_t* EY   = (ushort_t*)(base + off); off += (size_t)BB*MIDC*HWSZ*2;  // 77,070,336
    float* sums    = (float*)(base + off);    off += BB*MIDC*4;
    float* sews    = (float*)(base + off);    off += BB*MIDC*4;
    ushort_t* Aexp = (ushort_t*)(base + off); off += MIDC*CING*2;
    ushort_t* Aproj= (ushort_t*)(base + off); off += COUTC*MIDC*2;
    float* ebias   = (float*)(base + off);    off += MIDC*4;
    float* w9f     = (float*)(base + off);    off += MIDC*9*4;
    float* cstf    = (float*)(base + off);    off += MIDC*4;
    float* pscf    = (float*)(base + off);    off += COUTC*4;
    float* pshf    = (float*)(base + off);    off += COUTC*4;

    k0_setup<<<dim3(37), dim3(256), 0, stream>>>(
        expand_w, expand_bn, dw_w, dw_bn, id_w, id_bn, merge_bn, proj_w, proj_bn,
        Aexp, ebias, w9f, cstf, Aproj, pscf, pshf);
    k1_expand<<<dim3(HWSZ/64, BB), dim3(256), 0, stream>>>(x, Aexp, ebias, EY);
    k2_dw<<<dim3(MIDC/4, BB), dim3(256), 0, stream>>>(EY, w9f, cstf, sums);
    k3_se<<<dim3(BB), dim3(192), 0, stream>>>(
        sums, se_red_w, se_red_b, se_exp_w, se_exp_b, sews);
    k4_proj<<<dim3(HWSZ/64, BB), dim3(256), 0, stream>>>(
        EY, sews, Aproj, pscf, pshf, x, (float*)d_out);
}